// Round 4
// baseline (350.757 us; speedup 1.0000x reference)
//
#include <hip/hip_runtime.h>
#include <stdint.h>

#define BTOT 512
#define SQLEN 512
#define TTAB 20
#define EMB 32
#define DDIM 322            // E*10+2
#define KP 352              // padded K (11*32)
#define NP 352              // padded N (22*16)
#define MBLK 64             // rows per block
#define LDA 360             // A_lds row stride in bf16 elems (720B -> 2-way banks)
#define LDB 40              // B_lds row stride in bf16 elems (80B  -> 2-way banks)

typedef __attribute__((ext_vector_type(4))) float f32x4;
typedef __attribute__((ext_vector_type(8))) __bf16 bf16x8;
typedef __attribute__((ext_vector_type(4))) unsigned int u32x4;

static __device__ __forceinline__ unsigned short f2bf(float f) {
    unsigned int u = __float_as_uint(f);
    u += 0x7fffu + ((u >> 16) & 1u);   // round-to-nearest-even
    return (unsigned short)(u >> 16);
}

// Kernel 0: W (322x322 f32, row-major [o][d]) -> bf16 zero-padded [352][352] in ws
__global__ void prep_w(const float* __restrict__ W, unsigned short* __restrict__ wb) {
    int idx = blockIdx.x * 256 + threadIdx.x;
    if (idx >= NP * KP) return;
    int n = idx / KP;
    int k = idx - n * KP;
    float v = (n < DDIM && k < DDIM) ? W[n * DDIM + k] : 0.0f;
    wb[idx] = f2bf(v);
}

__global__ __launch_bounds__(256) void fused_embed_gemm(
    const float* __restrict__ feature,       // [BT*SQ][12]
    const float* __restrict__ join_tables,   // [BT][20][32]
    const float* __restrict__ type_embed,    // [32][32]
    const float* __restrict__ column_embed,  // [300][32]
    const unsigned short* __restrict__ wb,   // [352][352] bf16 (o x d)
    const float* __restrict__ bias,          // [322]
    float* __restrict__ out)                 // [BT*SQ][322] f32
{
    __shared__ __align__(16) unsigned short A_lds[MBLK * LDA];  // 45 KB
    __shared__ __align__(16) unsigned short B_lds[NP * LDB];    // 28.2 KB
    __shared__ float F_lds[MBLK * 12];                          // 3 KB

    const int t = threadIdx.x;
    const long mbase = (long)blockIdx.x * MBLK;
    const int b = (int)(mbase >> 9);   // 64 | 512 => whole block in one batch

    // ---- stage the 64 feature rows (ids as f32 + costs) ----
    {
        const float* src = feature + mbase * 12;
        #pragma unroll
        for (int i = 0; i < 3; ++i) {
            int off = i * 256 + t;
            F_lds[off] = src[off];
        }
    }
    __syncthreads();

    // ---- gather embeddings into A_lds as bf16, two elems per thread-iter ----
    // layout per row d: [0,32) type | [32,64) table | [64,128) cols |
    // [128,224) join | [224,320) joincols | 320,321 cost | [322,360) zero-pad
    const float* jtb = join_tables + (long)b * (TTAB * EMB);
    #pragma unroll 3
    for (int i = 0; i < 45; ++i) {                 // 64 rows * 180 pairs / 256 thr
        int pidx = i * 256 + t;
        int row = pidx / 180;
        int p = pidx - row * 180;
        int d = p << 1;
        int c = d >> 5;
        int j = d & 31;
        float v0 = 0.f, v1 = 0.f;
        if (c < 10) {
            int id = (int)F_lds[row * 12 + c];
            const float* src;
            bool nz = true;
            if (c == 0)                        { src = type_embed + id * EMB;  nz = (id != 0); }
            else if (c == 1 || (c >= 4 && c <= 6)) { src = jtb + id * EMB; }
            else                               { src = column_embed + id * EMB; nz = (id != 0); }
            if (nz) { v0 = src[j]; v1 = src[j + 1]; }
        } else if (d == 320) {
            v0 = F_lds[row * 12 + 10];
            v1 = F_lds[row * 12 + 11];
        }
        unsigned int pk = (unsigned int)f2bf(v0) | ((unsigned int)f2bf(v1) << 16);
        *reinterpret_cast<unsigned int*>(&A_lds[row * LDA + d]) = pk;
    }

    // ---- MFMA GEMM: 4 waves as 2M x 2N, wave tile 32 x 176 ----
    const int lane = t & 63;
    const int wid  = t >> 6;
    const int wm   = wid >> 1;
    const int wn   = wid & 1;
    const int l15  = lane & 15;
    const int lq   = lane >> 4;

    f32x4 acc[2][11];
    #pragma unroll
    for (int mf = 0; mf < 2; ++mf)
        #pragma unroll
        for (int nf = 0; nf < 11; ++nf)
            acc[mf][nf] = (f32x4){0.f, 0.f, 0.f, 0.f};

    const int arow0 = (wm * 32 + l15) * LDA + lq * 8;
    const int brow0 = (wn * 176 + l15) * LDB + lq * 8;

    for (int ks = 0; ks < 11; ++ks) {
        __syncthreads();                       // B_lds reuse guard
        // stage B k-slice: all 352 rows of W, 32 bf16 each (16B per thread)
        {
            const int rr = t >> 2;             // 0..63
            const int ko = (t & 3) * 8;        // 0,8,16,24
            #pragma unroll
            for (int it = 0; it < 6; ++it) {
                int n = it * 64 + rr;
                if (n < NP) {
                    u32x4 v = *reinterpret_cast<const u32x4*>(wb + (long)n * KP + ks * 32 + ko);
                    *reinterpret_cast<u32x4*>(&B_lds[n * LDB + ko]) = v;
                }
            }
        }
        __syncthreads();

        bf16x8 a0 = *reinterpret_cast<const bf16x8*>(&A_lds[arow0 + ks * 32]);
        bf16x8 a1 = *reinterpret_cast<const bf16x8*>(&A_lds[arow0 + 16 * LDA + ks * 32]);
        #pragma unroll
        for (int nf = 0; nf < 11; ++nf) {
            bf16x8 bq = *reinterpret_cast<const bf16x8*>(&B_lds[brow0 + nf * 16 * LDB]);
            acc[0][nf] = __builtin_amdgcn_mfma_f32_16x16x32_bf16(a0, bq, acc[0][nf], 0, 0, 0);
            acc[1][nf] = __builtin_amdgcn_mfma_f32_16x16x32_bf16(a1, bq, acc[1][nf], 0, 0, 0);
        }
    }

    // ---- epilogue: +bias, leaky_relu, store f32 (drop padded cols) ----
    #pragma unroll
    for (int nf = 0; nf < 11; ++nf) {
        int col = wn * 176 + nf * 16 + l15;
        if (col < DDIM) {
            float bv = bias[col];
            #pragma unroll
            for (int mf = 0; mf < 2; ++mf) {
                long rbase = mbase + wm * 32 + mf * 16 + lq * 4;
                #pragma unroll
                for (int r = 0; r < 4; ++r) {
                    float x = acc[mf][nf][r] + bv;
                    x = (x > 0.f) ? x : 0.01f * x;
                    out[(rbase + r) * DDIM + col] = x;
                }
            }
        }
    }
}

extern "C" void kernel_launch(void* const* d_in, const int* in_sizes, int n_in,
                              void* d_out, int out_size, void* d_ws, size_t ws_size,
                              hipStream_t stream) {
    const float* feature      = (const float*)d_in[0];
    const float* join_tables  = (const float*)d_in[1];
    const float* type_embed   = (const float*)d_in[2];
    const float* column_embed = (const float*)d_in[3];
    const float* W            = (const float*)d_in[4];
    const float* bias         = (const float*)d_in[5];
    float* out = (float*)d_out;
    unsigned short* wb = (unsigned short*)d_ws;   // 352*352*2 = 248 KB

    hipLaunchKernelGGL(prep_w, dim3((NP * KP + 255) / 256), dim3(256), 0, stream, W, wb);

    const int nblocks = (BTOT * SQLEN) / MBLK;    // 4096
    hipLaunchKernelGGL(fused_embed_gemm, dim3(nblocks), dim3(256), 0, stream,
                       feature, join_tables, type_embed, column_embed, wb, bias, out);
}

// Round 5
// 284.630 us; speedup vs baseline: 1.2323x; 1.2323x over previous
//
#include <hip/hip_runtime.h>
#include <stdint.h>

#define BTOT 512
#define SQLEN 512
#define TTAB 20
#define EMB 32
#define DDIM 322            // E*10+2
#define KP 352              // padded K (11*32)
#define NP 352              // padded N (22*16)
#define MBLK 64             // rows per block
#define LDA 360             // A_lds row stride in bf16 elems (720B)
#define NFRAG 22            // total 16-wide N fragments
#define KSLICES 11          // K/32

typedef __attribute__((ext_vector_type(4))) float f32x4;
typedef __attribute__((ext_vector_type(8))) __bf16 bf16x8;

static __device__ __forceinline__ unsigned short f2bf(float f) {
    unsigned int u = __float_as_uint(f);
    u += 0x7fffu + ((u >> 16) & 1u);   // round-to-nearest-even
    return (unsigned short)(u >> 16);
}

// W [322][322] f32 (row-major o x d) -> wb2: bf16 fragments in MFMA lane order.
// elem (n,k) -> frag ((k>>5)*22 + (n>>4)), lane ((n&15) + (((k>>3)&3)<<4)), e (k&7)
// so a wave's B-fragment load is wb2 + frag*512 + lane*8 : contiguous 1KB.
__global__ void prep_w(const float* __restrict__ W, unsigned short* __restrict__ wb2) {
    int idx = blockIdx.x * 256 + threadIdx.x;
    if (idx >= NP * KP) return;
    int n = idx / KP;
    int k = idx - n * KP;
    float v = (n < DDIM && k < DDIM) ? W[n * DDIM + k] : 0.0f;
    int dst = ((k >> 5) * NFRAG + (n >> 4)) * 512
            + ((n & 15) + (((k >> 3) & 3) << 4)) * 8 + (k & 7);
    wb2[dst] = f2bf(v);
}

__global__ __launch_bounds__(256, 3) void fused_embed_gemm(
    const float* __restrict__ feature,       // [BT*SQ][12]
    const float* __restrict__ join_tables,   // [BT][20][32]
    const float* __restrict__ type_embed,    // [32][32]
    const float* __restrict__ column_embed,  // [300][32]
    const unsigned short* __restrict__ wb2,  // permuted bf16 W fragments
    const float* __restrict__ bias,          // [322]
    float* __restrict__ out)                 // [BT*SQ][322] f32
{
    __shared__ __align__(16) unsigned short A_lds[MBLK * LDA];  // 45 KB
    __shared__ float F_lds[MBLK * 12];                          // 3 KB

    const int t = threadIdx.x;
    const long mbase = (long)blockIdx.x * MBLK;
    const int b = (int)(mbase >> 9);   // 64 | 512 => whole block in one batch

    // ---- stage the 64 feature rows ----
    {
        const float* src = feature + mbase * 12;
        #pragma unroll
        for (int i = 0; i < 3; ++i) {
            int off = i * 256 + t;
            F_lds[off] = src[off];
        }
    }
    __syncthreads();

    // ---- gather embeddings into A_lds as bf16, 4 elems (float4) per iter ----
    // row layout d: [0,32) type | [32,64) table | [64,128) cols |
    // [128,224) join | [224,320) joincols | 320,321 cost | [322,360) zero-pad
    const float* jtb = join_tables + (long)b * (TTAB * EMB);
    #pragma unroll 4
    for (int i = 0; i < 20; ++i) {              // 64 rows * 80 quads / 256 thr
        int pidx = i * 256 + t;
        int row = pidx / 80;
        int q = pidx - row * 80;
        int d = q << 2;
        int c = q >> 3;
        int j = d & 31;
        float4 v = make_float4(0.f, 0.f, 0.f, 0.f);
        int id = (int)F_lds[row * 12 + c];
        const float* src;
        bool nz = true;
        if (c == 0)                            { src = type_embed + id * EMB;  nz = (id != 0); }
        else if (c == 1 || (c >= 4 && c <= 6)) { src = jtb + id * EMB; }
        else                                   { src = column_embed + id * EMB; nz = (id != 0); }
        if (nz) v = *reinterpret_cast<const float4*>(src + j);
        uint2 pk;
        pk.x = (unsigned int)f2bf(v.x) | ((unsigned int)f2bf(v.y) << 16);
        pk.y = (unsigned int)f2bf(v.z) | ((unsigned int)f2bf(v.w) << 16);
        *reinterpret_cast<uint2*>(&A_lds[row * LDA + d]) = pk;
    }
    // ---- cost pair + zero pad: d in [320,360), 10 quads per row ----
    #pragma unroll
    for (int i = 0; i < 3; ++i) {
        int pidx = i * 256 + t;
        if (pidx < 640) {
            int row = pidx / 10;
            int gi = pidx - row * 10;
            int d = 320 + (gi << 2);
            uint2 pk = make_uint2(0u, 0u);
            if (gi == 0) {
                pk.x = (unsigned int)f2bf(F_lds[row * 12 + 10])
                     | ((unsigned int)f2bf(F_lds[row * 12 + 11]) << 16);
            }
            *reinterpret_cast<uint2*>(&A_lds[row * LDA + d]) = pk;
        }
    }
    __syncthreads();

    // ---- MFMA GEMM: 4 waves as 2M x 2N, wave tile 32 x 176, NO barriers ----
    const int lane = t & 63;
    const int wid  = t >> 6;
    const int wm   = wid >> 1;
    const int wn   = wid & 1;
    const int l15  = lane & 15;
    const int lq   = lane >> 4;

    f32x4 acc[2][11];
    #pragma unroll
    for (int mf = 0; mf < 2; ++mf)
        #pragma unroll
        for (int nf = 0; nf < 11; ++nf)
            acc[mf][nf] = (f32x4){0.f, 0.f, 0.f, 0.f};

    const int arow0 = (wm * 32 + l15) * LDA + lq * 8;
    const unsigned short* bbase = wb2 + ((long)(wn * 11) * 512) + lane * 8;

    #pragma unroll 2
    for (int ks = 0; ks < KSLICES; ++ks) {
        bf16x8 a0 = *reinterpret_cast<const bf16x8*>(&A_lds[arow0 + ks * 32]);
        bf16x8 a1 = *reinterpret_cast<const bf16x8*>(&A_lds[arow0 + 16 * LDA + ks * 32]);
        #pragma unroll
        for (int nf = 0; nf < 11; ++nf) {
            bf16x8 bq = *reinterpret_cast<const bf16x8*>(bbase + (long)(ks * NFRAG + nf) * 512);
            acc[0][nf] = __builtin_amdgcn_mfma_f32_16x16x32_bf16(a0, bq, acc[0][nf], 0, 0, 0);
            acc[1][nf] = __builtin_amdgcn_mfma_f32_16x16x32_bf16(a1, bq, acc[1][nf], 0, 0, 0);
        }
    }

    // ---- epilogue: +bias, leaky_relu, store f32 (drop padded cols) ----
    #pragma unroll
    for (int nf = 0; nf < 11; ++nf) {
        int col = wn * 176 + nf * 16 + l15;
        if (col < DDIM) {
            float bv = bias[col];
            #pragma unroll
            for (int mf = 0; mf < 2; ++mf) {
                long rbase = mbase + wm * 32 + mf * 16 + lq * 4;
                #pragma unroll
                for (int r = 0; r < 4; ++r) {
                    float x = acc[mf][nf][r] + bv;
                    x = (x > 0.f) ? x : 0.01f * x;
                    out[(rbase + r) * DDIM + col] = x;
                }
            }
        }
    }
}

extern "C" void kernel_launch(void* const* d_in, const int* in_sizes, int n_in,
                              void* d_out, int out_size, void* d_ws, size_t ws_size,
                              hipStream_t stream) {
    const float* feature      = (const float*)d_in[0];
    const float* join_tables  = (const float*)d_in[1];
    const float* type_embed   = (const float*)d_in[2];
    const float* column_embed = (const float*)d_in[3];
    const float* W            = (const float*)d_in[4];
    const float* bias         = (const float*)d_in[5];
    float* out = (float*)d_out;
    unsigned short* wb2 = (unsigned short*)d_ws;   // 11*22*512*2 = 248 KB

    hipLaunchKernelGGL(prep_w, dim3((NP * KP + 255) / 256), dim3(256), 0, stream, W, wb2);

    const int nblocks = (BTOT * SQLEN) / MBLK;    // 4096
    hipLaunchKernelGGL(fused_embed_gemm, dim3(nblocks), dim3(256), 0, stream,
                       feature, join_tables, type_embed, column_embed, wb2, bias, out);
}

// Round 6
// 200.416 us; speedup vs baseline: 1.7501x; 1.4202x over previous
//
#include <hip/hip_runtime.h>
#include <stdint.h>

#define BTOT 512
#define SQLEN 512
#define TTAB 20
#define EMB 32
#define DDIM 322            // E*10+2
#define KP 352              // padded K (11*32)
#define NP 384              // padded N (24*16) -> 6 frags per wave, 4 waves
#define MBLK 64             // rows per block
#define LDA 360             // A_lds row stride in bf16 elems (720B)
#define NFRAG 24            // total 16-wide N fragments
#define KSLICES 11          // K/32

typedef __attribute__((ext_vector_type(4))) float f32x4;
typedef __attribute__((ext_vector_type(8))) __bf16 bf16x8;

static __device__ __forceinline__ unsigned short f2bf(float f) {
    unsigned int u = __float_as_uint(f);
    u += 0x7fffu + ((u >> 16) & 1u);   // round-to-nearest-even
    return (unsigned short)(u >> 16);
}

// W [322][322] f32 (o x d) -> wb2 bf16 fragments in MFMA lane order.
// (n,k) -> frag ((k>>5)*24 + (n>>4)), lane ((n&15) | (((k>>3)&3)<<4)), e (k&7)
// A wave's B-fragment load = wb2 + frag*512 + lane*8 : contiguous 1KB.
__global__ void prep_w(const float* __restrict__ W, unsigned short* __restrict__ wb2) {
    int idx = blockIdx.x * 256 + threadIdx.x;
    if (idx >= NP * KP) return;
    int n = idx / KP;
    int k = idx - n * KP;
    float v = (n < DDIM && k < DDIM) ? W[n * DDIM + k] : 0.0f;
    int dst = ((k >> 5) * NFRAG + (n >> 4)) * 512
            + ((n & 15) + (((k >> 3) & 3) << 4)) * 8 + (k & 7);
    wb2[dst] = f2bf(v);
}

__global__ __launch_bounds__(256, 2) void fused_embed_gemm(
    const float* __restrict__ feature,       // [BT*SQ][12]
    const float* __restrict__ join_tables,   // [BT][20][32]
    const float* __restrict__ type_embed,    // [32][32]
    const float* __restrict__ column_embed,  // [300][32]
    const unsigned short* __restrict__ wb2,  // permuted bf16 W fragments
    const float* __restrict__ bias,          // [322]
    float* __restrict__ out)                 // [BT*SQ][322] f32
{
    __shared__ __align__(16) unsigned short A_lds[MBLK * LDA];  // 45 KB
    __shared__ float F_lds[MBLK * 12];                          // 3 KB

    const int t = threadIdx.x;
    const long mbase = (long)blockIdx.x * MBLK;
    const int b = (int)(mbase >> 9);   // 64 | 512 => whole block in one batch

    // ---- stage the 64 feature rows ----
    {
        const float* src = feature + mbase * 12;
        #pragma unroll
        for (int i = 0; i < 3; ++i) {
            int off = i * 256 + t;
            F_lds[off] = src[off];
        }
    }
    __syncthreads();

    // ---- gather embeddings into A_lds as bf16, float4 per iter ----
    // row layout d: [0,32) type | [32,64) table | [64,128) cols |
    // [128,224) join | [224,320) joincols | 320,321 cost | [322,360) zero-pad
    const float* jtb = join_tables + (long)b * (TTAB * EMB);
    #pragma unroll 4
    for (int i = 0; i < 20; ++i) {              // 64 rows * 80 quads / 256 thr
        int pidx = i * 256 + t;
        int row = pidx / 80;
        int q = pidx - row * 80;
        int d = q << 2;
        int c = q >> 3;
        int j = d & 31;
        float4 v = make_float4(0.f, 0.f, 0.f, 0.f);
        int id = (int)F_lds[row * 12 + c];
        const float* src;
        bool nz = true;
        if (c == 0)                            { src = type_embed + id * EMB;  nz = (id != 0); }
        else if (c == 1 || (c >= 4 && c <= 6)) { src = jtb + id * EMB; }
        else                                   { src = column_embed + id * EMB; nz = (id != 0); }
        if (nz) v = *reinterpret_cast<const float4*>(src + j);
        uint2 pk;
        pk.x = (unsigned int)f2bf(v.x) | ((unsigned int)f2bf(v.y) << 16);
        pk.y = (unsigned int)f2bf(v.z) | ((unsigned int)f2bf(v.w) << 16);
        *reinterpret_cast<uint2*>(&A_lds[row * LDA + d]) = pk;
    }
    // ---- cost pair + zero pad: d in [320,360) ----
    #pragma unroll
    for (int i = 0; i < 3; ++i) {
        int pidx = i * 256 + t;
        if (pidx < 640) {
            int row = pidx / 10;
            int gi = pidx - row * 10;
            int d = 320 + (gi << 2);
            uint2 pk = make_uint2(0u, 0u);
            if (gi == 0) {
                pk.x = (unsigned int)f2bf(F_lds[row * 12 + 10])
                     | ((unsigned int)f2bf(F_lds[row * 12 + 11]) << 16);
            }
            *reinterpret_cast<uint2*>(&A_lds[row * LDA + d]) = pk;
        }
    }
    __syncthreads();

    // ---- MFMA GEMM: 4 waves as 1M x 4N, wave tile 64 x 96, reg-dbuf B ----
    const int lane = t & 63;
    const int wn   = t >> 6;          // wave owns frags wn*6 .. wn*6+5
    const int l15  = lane & 15;
    const int lq   = lane >> 4;

    f32x4 acc[4][6];
    #pragma unroll
    for (int mf = 0; mf < 4; ++mf)
        #pragma unroll
        for (int nf = 0; nf < 6; ++nf)
            acc[mf][nf] = (f32x4){0.f, 0.f, 0.f, 0.f};

    const int arow0 = l15 * LDA + lq * 8;
    const unsigned short* bbase = wb2 + ((long)(wn * 6) * 512) + lane * 8;

    bf16x8 b0[6], b1[6];

#define LOAD_B(bank, ksl)                                                        \
    _Pragma("unroll")                                                            \
    for (int nf = 0; nf < 6; ++nf)                                               \
        bank[nf] = *reinterpret_cast<const bf16x8*>(bbase + (long)((ksl) * NFRAG + nf) * 512);

#define GEMM_STEP(bank, ksl) {                                                   \
    bf16x8 a0 = *reinterpret_cast<const bf16x8*>(&A_lds[arow0 + (ksl) * 32]);    \
    bf16x8 a1 = *reinterpret_cast<const bf16x8*>(&A_lds[arow0 + 16 * LDA + (ksl) * 32]); \
    bf16x8 a2 = *reinterpret_cast<const bf16x8*>(&A_lds[arow0 + 32 * LDA + (ksl) * 32]); \
    bf16x8 a3 = *reinterpret_cast<const bf16x8*>(&A_lds[arow0 + 48 * LDA + (ksl) * 32]); \
    _Pragma("unroll")                                                            \
    for (int nf = 0; nf < 6; ++nf) {                                             \
        acc[0][nf] = __builtin_amdgcn_mfma_f32_16x16x32_bf16(a0, bank[nf], acc[0][nf], 0, 0, 0); \
        acc[1][nf] = __builtin_amdgcn_mfma_f32_16x16x32_bf16(a1, bank[nf], acc[1][nf], 0, 0, 0); \
        acc[2][nf] = __builtin_amdgcn_mfma_f32_16x16x32_bf16(a2, bank[nf], acc[2][nf], 0, 0, 0); \
        acc[3][nf] = __builtin_amdgcn_mfma_f32_16x16x32_bf16(a3, bank[nf], acc[3][nf], 0, 0, 0); \
    } }

    LOAD_B(b0, 0);
    #pragma unroll
    for (int kp = 0; kp < 5; ++kp) {
        const int ks = kp * 2;
        LOAD_B(b1, ks + 1);
        GEMM_STEP(b0, ks);
        LOAD_B(b0, ks + 2);
        GEMM_STEP(b1, ks + 1);
    }
    GEMM_STEP(b0, 10);

    // ---- epilogue: +bias, leaky_relu, store f32 (drop padded cols) ----
    #pragma unroll
    for (int nf = 0; nf < 6; ++nf) {
        int col = wn * 96 + nf * 16 + l15;
        if (col < DDIM) {
            float bv = bias[col];
            #pragma unroll
            for (int mf = 0; mf < 4; ++mf) {
                long rbase = mbase + mf * 16 + lq * 4;
                #pragma unroll
                for (int r = 0; r < 4; ++r) {
                    float x = acc[mf][nf][r] + bv;
                    x = (x > 0.f) ? x : 0.01f * x;
                    out[(rbase + r) * DDIM + col] = x;
                }
            }
        }
    }
}

extern "C" void kernel_launch(void* const* d_in, const int* in_sizes, int n_in,
                              void* d_out, int out_size, void* d_ws, size_t ws_size,
                              hipStream_t stream) {
    const float* feature      = (const float*)d_in[0];
    const float* join_tables  = (const float*)d_in[1];
    const float* type_embed   = (const float*)d_in[2];
    const float* column_embed = (const float*)d_in[3];
    const float* W            = (const float*)d_in[4];
    const float* bias         = (const float*)d_in[5];
    float* out = (float*)d_out;
    unsigned short* wb2 = (unsigned short*)d_ws;   // 11*24*512*2 = 270 KB

    hipLaunchKernelGGL(prep_w, dim3((NP * KP + 255) / 256), dim3(256), 0, stream, W, wb2);

    const int nblocks = (BTOT * SQLEN) / MBLK;    // 4096
    hipLaunchKernelGGL(fused_embed_gemm, dim3(nblocks), dim3(256), 0, stream,
                       feature, join_tables, type_embed, column_embed, wb2, bias, out);
}